// Round 1
// baseline (539.600 us; speedup 1.0000x reference)
//
#include <hip/hip_runtime.h>

#define SEQ 512
#define BATCH 128
#define DIM 1024
#define T 32

// ---------------- W transpose: Wt[d][t] = W[t][d] ----------------
__global__ void k_wt(const float* __restrict__ W, float* __restrict__ Wt)
{
    int idx = blockIdx.x * 256 + threadIdx.x;   // 32768 total
    if (idx >= DIM * T) return;
    int d = idx >> 5, t = idx & 31;
    Wt[idx] = W[t * DIM + d];
}

// ---------------- emissions: e[s,b,t] = dot(features[s,b,:], W[t,:]) + bias[t] ----------------
__global__ __launch_bounds__(128) void k_emis(const float* __restrict__ A,
        const float* __restrict__ Wt, const float* __restrict__ bias,
        float* __restrict__ e)
{
    __shared__ __align__(16) float4 lds[128][9];   // 128 rows x 32 floats, padded
    int tid = threadIdx.x;
    int row0 = blockIdx.x * 128;

    float acc[T];
    #pragma unroll
    for (int t = 0; t < T; ++t) acc[t] = bias[t];

    int q = tid & 7;         // float4 slot within row chunk
    int rbase = tid >> 3;    // 0..15

    for (int dk = 0; dk < DIM; dk += 32) {
        #pragma unroll
        for (int it = 0; it < 8; ++it) {
            int r = rbase + it * 16;
            float4 v = *(const float4*)&A[(size_t)(row0 + r) * DIM + dk + q * 4];
            lds[r][q] = v;
        }
        __syncthreads();
        #pragma unroll
        for (int d4 = 0; d4 < 8; ++d4) {
            float4 a = lds[tid][d4];
            #pragma unroll
            for (int c = 0; c < 4; ++c) {
                float av = (&a.x)[c];
                const float* wrow = &Wt[(dk + d4 * 4 + c) * T];
                #pragma unroll
                for (int t = 0; t < T; ++t)
                    acc[t] = fmaf(av, wrow[t], acc[t]);
            }
        }
        __syncthreads();
    }

    float4* eo = (float4*)&e[(size_t)(row0 + tid) * T];
    #pragma unroll
    for (int t4 = 0; t4 < 8; ++t4) {
        float4 v;
        v.x = acc[t4 * 4 + 0]; v.y = acc[t4 * 4 + 1];
        v.z = acc[t4 * 4 + 2]; v.w = acc[t4 * 4 + 3];
        eo[t4] = v;
    }
}

// ---------------- recursions: role 0=alpha, 1=beta, 2=viterbi; one wave per (role,b) ----------------
__global__ __launch_bounds__(64) void k_rec(const float* __restrict__ e,
        const int* __restrict__ mask,
        const float* __restrict__ trans,
        const float* __restrict__ start,
        const float* __restrict__ endp,
        float* __restrict__ pa, float* __restrict__ pb,
        double* __restrict__ Ca, double* __restrict__ Cb,
        float* __restrict__ tags_out)
{
    __shared__ __align__(16) float pbuf[T];
    __shared__ unsigned char hist[(SEQ - 1) * T];

    int role = blockIdx.x >> 7;     // /128
    int b    = blockIdx.x & 127;
    int tid  = threadIdx.x;
    int kh   = tid >> 5;            // which k-half this lane sums
    int j    = tid & 31;            // output state

    if (role == 0) {
        // ---- alpha (forward), prob domain ----
        float Etc[16];
        #pragma unroll
        for (int kk = 0; kk < 16; ++kk)
            Etc[kk] = expf(trans[(kh * 16 + kk) * T + j]);

        float a0 = e[(0 * BATCH + b) * T + j] + start[j];
        float m = a0;
        #pragma unroll
        for (int d = 1; d < 32; d <<= 1) m = fmaxf(m, __shfl_xor(m, d));
        float v = expf(a0 - m);
        float s = v;
        #pragma unroll
        for (int d = 1; d < 32; d <<= 1) s += __shfl_xor(s, d);
        float p = v / s;
        double C = (double)m + (double)logf(s);
        if (tid < 32) pa[(size_t)(0 * BATCH + b) * T + j] = p;
        if (tid == 0) Ca[0 * BATCH + b] = C;

        for (int i = 1; i < SEQ; ++i) {
            __syncthreads();
            if (tid < 32) pbuf[j] = p;
            __syncthreads();
            const float4* p4 = (const float4*)pbuf;
            float q = 0.f;
            #pragma unroll
            for (int n = 0; n < 4; ++n) {
                float4 pv = p4[kh * 4 + n];
                q = fmaf(pv.x, Etc[n * 4 + 0], q);
                q = fmaf(pv.y, Etc[n * 4 + 1], q);
                q = fmaf(pv.z, Etc[n * 4 + 2], q);
                q = fmaf(pv.w, Etc[n * 4 + 3], q);
            }
            q += __shfl_xor(q, 32);
            float ee = expf(e[(size_t)(i * BATCH + b) * T + j]);
            float vv = q * ee;
            float ss = vv;
            #pragma unroll
            for (int d = 1; d < 32; d <<= 1) ss += __shfl_xor(ss, d);
            int mk = mask[i * BATCH + b];
            if (mk) {
                p = vv / ss;
                C += (double)logf(ss);
            }
            if (tid < 32) pa[(size_t)(i * BATCH + b) * T + j] = p;
            if (tid == 0) Ca[i * BATCH + b] = C;
        }
    } else if (role == 1) {
        // ---- beta (backward), prob domain ----
        float Etr[16];
        #pragma unroll
        for (int kk = 0; kk < 16; ++kk)
            Etr[kk] = expf(trans[j * T + kh * 16 + kk]);

        float v0 = endp[j];
        float m = v0;
        #pragma unroll
        for (int d = 1; d < 32; d <<= 1) m = fmaxf(m, __shfl_xor(m, d));
        float v = expf(v0 - m);
        float s = v;
        #pragma unroll
        for (int d = 1; d < 32; d <<= 1) s += __shfl_xor(s, d);
        float p = v / s;
        double C = (double)m + (double)logf(s);
        if (tid < 32) pb[(size_t)((SEQ - 1) * BATCH + b) * T + j] = p;
        if (tid == 0) Cb[(SEQ - 1) * BATCH + b] = C;

        for (int i = SEQ - 1; i >= 1; --i) {
            __syncthreads();
            if (tid < 32)
                pbuf[j] = p * expf(e[(size_t)(i * BATCH + b) * T + j]);
            __syncthreads();
            const float4* p4 = (const float4*)pbuf;
            float q = 0.f;
            #pragma unroll
            for (int n = 0; n < 4; ++n) {
                float4 pv = p4[kh * 4 + n];
                q = fmaf(pv.x, Etr[n * 4 + 0], q);
                q = fmaf(pv.y, Etr[n * 4 + 1], q);
                q = fmaf(pv.z, Etr[n * 4 + 2], q);
                q = fmaf(pv.w, Etr[n * 4 + 3], q);
            }
            q += __shfl_xor(q, 32);
            float ss = q;
            #pragma unroll
            for (int d = 1; d < 32; d <<= 1) ss += __shfl_xor(ss, d);
            int mk = mask[i * BATCH + b];
            if (mk) {
                p = q / ss;
                C += (double)logf(ss);
            }
            if (tid < 32) pb[(size_t)((i - 1) * BATCH + b) * T + j] = p;
            if (tid == 0) Cb[(i - 1) * BATCH + b] = C;
        }
    } else {
        // ---- viterbi (log domain, max-plus) ----
        float trv[16];
        #pragma unroll
        for (int kk = 0; kk < 16; ++kk)
            trv[kk] = trans[(kh * 16 + kk) * T + j];

        float sc = start[j] + e[(0 * BATCH + b) * T + j];

        for (int i = 1; i < SEQ; ++i) {
            __syncthreads();
            if (tid < 32) pbuf[j] = sc;
            __syncthreads();
            float ej = e[(size_t)(i * BATCH + b) * T + j];
            const float4* p4 = (const float4*)pbuf;
            float best = -INFINITY; int bi = 0;
            #pragma unroll
            for (int n = 0; n < 4; ++n) {
                float4 pv = p4[kh * 4 + n];
                float c0 = (pv.x + trv[n * 4 + 0]) + ej;
                float c1 = (pv.y + trv[n * 4 + 1]) + ej;
                float c2 = (pv.z + trv[n * 4 + 2]) + ej;
                float c3 = (pv.w + trv[n * 4 + 3]) + ej;
                if (c0 > best) { best = c0; bi = kh * 16 + n * 4 + 0; }
                if (c1 > best) { best = c1; bi = kh * 16 + n * 4 + 1; }
                if (c2 > best) { best = c2; bi = kh * 16 + n * 4 + 2; }
                if (c3 > best) { best = c3; bi = kh * 16 + n * 4 + 3; }
            }
            float ob = __shfl_xor(best, 32);
            int   obi = __shfl_xor(bi, 32);
            // lower-k half wins ties (first-index argmax semantics)
            float bl = kh ? ob : best;  int il = kh ? obi : bi;
            float bh = kh ? best : ob;  int ih = kh ? bi : obi;
            float nb; int nbi;
            if (bh > bl) { nb = bh; nbi = ih; } else { nb = bl; nbi = il; }
            if (tid < 32) hist[(i - 1) * T + j] = (unsigned char)nbi;
            int mk = mask[i * BATCH + b];
            if (mk) sc = nb;
        }
        // last = argmax_j(score + end), first index on ties
        float fs = sc + endp[j];
        int fj = j;
        #pragma unroll
        for (int d = 1; d < 32; d <<= 1) {
            float ov = __shfl_xor(fs, d);
            int oj = __shfl_xor(fj, d);
            if (ov > fs || (ov == fs && oj < fj)) { fs = ov; fj = oj; }
        }
        __syncthreads();
        if (tid == 0) {
            int tag = fj;
            tags_out[(SEQ - 1) * BATCH + b] = (float)tag;
            for (int i = SEQ - 2; i >= 0; --i) {
                tag = hist[i * T + tag];
                tags_out[i * BATCH + b] = (float)tag;
            }
        }
    }
}

// ---------------- z[b] = logsumexp_t(alpha[S-1,b,t] + end[t]) ----------------
__global__ void k_z(const float* __restrict__ pa, const double* __restrict__ Ca,
                    const float* __restrict__ endp, double* __restrict__ zd)
{
    int b = threadIdx.x;     // 128 threads, 1 block
    if (b >= BATCH) return;
    const float* row = &pa[(size_t)((SEQ - 1) * BATCH + b) * T];
    float s = 0.f;
    #pragma unroll
    for (int t = 0; t < T; ++t) s += row[t] * expf(endp[t]);
    zd[b] = Ca[(SEQ - 1) * BATCH + b] + (double)logf(s);
}

// ---------------- probs = pa * pb * exp(Ca + Cb - z) ----------------
__global__ __launch_bounds__(256) void k_probs(const float* __restrict__ pa,
        const float* __restrict__ pb, const double* __restrict__ Ca,
        const double* __restrict__ Cb, const double* __restrict__ zd,
        float* __restrict__ out)
{
    int idx = blockIdx.x * 256 + threadIdx.x;   // float4 index, 524288 total
    int ib = idx >> 3;                          // (i*BATCH + b)
    int b = ib & (BATCH - 1);
    double ex = Ca[ib] + Cb[ib] - zd[b];
    float scl = expf((float)ex);
    float4 a = ((const float4*)pa)[idx];
    float4 c = ((const float4*)pb)[idx];
    float4 o;
    o.x = a.x * c.x * scl;
    o.y = a.y * c.y * scl;
    o.z = a.z * c.z * scl;
    o.w = a.w * c.w * scl;
    ((float4*)out)[idx] = o;
}

extern "C" void kernel_launch(void* const* d_in, const int* in_sizes, int n_in,
                              void* d_out, int out_size, void* d_ws, size_t ws_size,
                              hipStream_t stream) {
    const float* features = (const float*)d_in[0];
    const int*   mask     = (const int*)d_in[1];
    const float* W        = (const float*)d_in[2];
    const float* bias     = (const float*)d_in[3];
    const float* trans    = (const float*)d_in[4];
    const float* startp   = (const float*)d_in[5];
    const float* endp     = (const float*)d_in[6];

    char* ws = (char*)d_ws;
    // doubles first (8B aligned)
    double* Ca = (double*)(ws + 0);                      // 65536 doubles
    double* Cb = (double*)(ws + 524288);                 // 65536 doubles
    double* zd = (double*)(ws + 1048576);                // 128 doubles
    float*  Wt = (float*)(ws + 1049600);                 // 32768 floats
    float*  e  = (float*)(ws + 1180672);                 // 2097152 floats
    float*  pa = (float*)(ws + 9569280);                 // 2097152 floats
    float*  pb = (float*)(ws + 17957888);                // 2097152 floats

    float* probs_out = (float*)d_out;
    float* tags_out  = probs_out + (size_t)SEQ * BATCH * T;

    k_wt<<<128, 256, 0, stream>>>(W, Wt);
    k_emis<<<512, 128, 0, stream>>>(features, Wt, bias, e);
    k_rec<<<384, 64, 0, stream>>>(e, mask, trans, startp, endp,
                                  pa, pb, Ca, Cb, tags_out);
    k_z<<<1, 128, 0, stream>>>(pa, Ca, endp, zd);
    k_probs<<<2048, 256, 0, stream>>>(pa, pb, Ca, Cb, zd, probs_out);
}